// Round 7
// baseline (123.221 us; speedup 1.0000x reference)
//
#include <hip/hip_runtime.h>

#define IN_F     4096
#define OUT_F    11008
#define NGROUP   512                 // IN_F / 8
#define BATCH    4
#define CBSIZE   65536
#define NSLICE   16
#define SLICE_ENT (CBSIZE / NSLICE)  // 4096 entries per slice
#define CAP      96                  // bucket capacity: mean 32, +11.7 sigma
#define ROWBLK   16                  // main grid.x
#define ROWS_PER_BLOCK (OUT_F / ROWBLK)  // 688
#define OTILES   (OUT_F / 256)       // 43

typedef unsigned int uv4 __attribute__((ext_vector_type(4)));
typedef float        fv4 __attribute__((ext_vector_type(4)));

__device__ __forceinline__ unsigned bf16rne(float f) {
    unsigned u = __float_as_uint(f);
    return (u + 0x7fffu + ((u >> 16) & 1u)) >> 16;
}
__device__ __forceinline__ float blo(unsigned u) { return __uint_as_float(u << 16); }
__device__ __forceinline__ float bhi(unsigned u) { return __uint_as_float(u & 0xffff0000u); }

// Pack fp32 codebook [65536][8] -> bf16x2 [65536][4] u32 (16 B/entry).
__global__ __launch_bounds__(256) void pack_cb_kernel(
    const float* __restrict__ cb, unsigned* __restrict__ cbh)
{
    const int e = blockIdx.x * 256 + threadIdx.x;   // 256*256 = 65536
    const fv4* src = (const fv4*)(cb + (size_t)e * 8);
    const fv4 a = src[0];
    const fv4 b = src[1];
    uv4 p;
    p.x = bf16rne(a.x) | (bf16rne(a.y) << 16);
    p.y = bf16rne(a.z) | (bf16rne(a.w) << 16);
    p.z = bf16rne(b.x) | (bf16rne(b.y) << 16);
    p.w = bf16rne(b.z) | (bf16rne(b.w) << 16);
    *((uv4*)(cbh + (size_t)e * 4)) = p;
}

// out[b][o] = bias[o]
__global__ __launch_bounds__(256) void init_out_kernel(
    const float* __restrict__ bias, float* __restrict__ out)
{
    const int o = blockIdx.x * 256 + threadIdx.x;
    out[(size_t)blockIdx.y * OUT_F + o] = bias[o];
}

// One wave per output row: bin the row's 512 codes into 16 slice-buckets.
// Entry = (g<<12) | (code & 4095). LDS atomic counters give compact buckets.
__global__ __launch_bounds__(64) void bin_kernel(
    const int* __restrict__ codes,      // [11008][512]
    unsigned*  __restrict__ buckets,    // [11008][16][CAP]
    unsigned*  __restrict__ counts)     // [11008][16]
{
    __shared__ unsigned cnt[NSLICE];
    const int r = blockIdx.x;
    const int lane = threadIdx.x;
    if (lane < NSLICE) cnt[lane] = 0;
    __syncthreads();

    const int* crow = codes + (size_t)r * NGROUP;
#pragma unroll
    for (int j = 0; j < NGROUP / 64; ++j) {
        const int g = j * 64 + lane;
        const unsigned c = (unsigned)crow[g];        // coalesced
        const unsigned s = c >> 12;                  // slice
        const unsigned e = ((unsigned)g << 12) | (c & 4095u);
        const unsigned pos = atomicAdd(&cnt[s], 1u);
        if (pos < CAP)
            buckets[((size_t)r * NSLICE + s) * CAP + pos] = e;
    }
    __syncthreads();
    if (lane < NSLICE) counts[(size_t)r * NSLICE + lane] = cnt[lane];
}

// Block = (row-chunk, slice). LDS: cb slice (64 KB) + x as packed bf16 (32 KB).
// Per row: 32 lanes stream the bucket (coalesced global), gather cb+x from
// LDS (no TCP fill cap!), FMA, half-wave shfl reduce, atomicAdd per batch.
__global__ __launch_bounds__(1024) void main_kernel(
    const float*    __restrict__ x,        // [4][4096] fp32
    const unsigned* __restrict__ cbh,      // [65536][4] packed bf16x2
    const unsigned* __restrict__ buckets,  // [11008][16][CAP]
    const unsigned* __restrict__ counts,   // [11008][16]
    const float*    __restrict__ scales,   // [11008]
    float*          __restrict__ out)      // [4][11008]
{
    extern __shared__ unsigned lds[];          // 96 KB
    unsigned* cbl = lds;                       // [SLICE_ENT*4]  64 KB
    unsigned* xl  = lds + SLICE_ENT * 4;       // [NGROUP*16]    32 KB

    const int tid = threadIdx.x;
    const int s   = blockIdx.y;

    // Stage codebook slice: 4096 x 16 B, coalesced dwordx4.
    {
        const uv4* src = (const uv4*)cbh + (size_t)s * SLICE_ENT;
        uv4* dst = (uv4*)cbl;
        for (int i = tid; i < SLICE_ENT; i += 1024) dst[i] = src[i];
    }
    // Stage x as bf16x2, layout word[(g*4 + b)*4 + w] = feats {2w, 2w+1}.
    for (int i = tid; i < NGROUP * 16; i += 1024) {
        const int g = i >> 4, b = (i >> 2) & 3, w = i & 3;
        const float* p = x + (size_t)b * IN_F + g * 8 + w * 2;
        xl[i] = bf16rne(p[0]) | (bf16rne(p[1]) << 16);
    }
    __syncthreads();

    const int wave = tid >> 6;
    const int lane = tid & 63;
    const int half = lane >> 5;
    const int l5   = lane & 31;
    const int rbase = blockIdx.x * ROWS_PER_BLOCK;

    for (int it = 0; it < (ROWS_PER_BLOCK + 31) / 32; ++it) {
        const int  lr    = it * 32 + wave * 2 + half;   // 2 rows per wave
        const bool rowok = lr < ROWS_PER_BLOCK;
        const int  r     = rbase + (rowok ? lr : 0);
        unsigned cnt = rowok ? counts[(size_t)r * NSLICE + s] : 0u;
        if (cnt > CAP) cnt = CAP;
        const unsigned* brow = buckets + ((size_t)r * NSLICE + s) * CAP;

        float a0 = 0.f, a1 = 0.f, a2 = 0.f, a3 = 0.f;
        for (unsigned off = (unsigned)l5; ; off += 32) {
            const bool act = off < cnt;
            if (__ballot(act) == 0ull) break;
            if (act) {
                const unsigned e   = brow[off];          // coalesced 128 B/half
                const unsigned g   = e >> 12;
                const unsigned clo = e & 4095u;
                const uv4 cw = ((const uv4*)cbl)[clo];   // 16 B LDS gather
                const uv4 x0 = ((const uv4*)xl)[g * 4 + 0];
                const uv4 x1 = ((const uv4*)xl)[g * 4 + 1];
                const uv4 x2 = ((const uv4*)xl)[g * 4 + 2];
                const uv4 x3 = ((const uv4*)xl)[g * 4 + 3];
                const float c0 = blo(cw.x), c1 = bhi(cw.x), c2 = blo(cw.y), c3 = bhi(cw.y);
                const float c4 = blo(cw.z), c5 = bhi(cw.z), c6 = blo(cw.w), c7 = bhi(cw.w);
                a0 += c0*blo(x0.x) + c1*bhi(x0.x) + c2*blo(x0.y) + c3*bhi(x0.y)
                    + c4*blo(x0.z) + c5*bhi(x0.z) + c6*blo(x0.w) + c7*bhi(x0.w);
                a1 += c0*blo(x1.x) + c1*bhi(x1.x) + c2*blo(x1.y) + c3*bhi(x1.y)
                    + c4*blo(x1.z) + c5*bhi(x1.z) + c6*blo(x1.w) + c7*bhi(x1.w);
                a2 += c0*blo(x2.x) + c1*bhi(x2.x) + c2*blo(x2.y) + c3*bhi(x2.y)
                    + c4*blo(x2.z) + c5*bhi(x2.z) + c6*blo(x2.w) + c7*bhi(x2.w);
                a3 += c0*blo(x3.x) + c1*bhi(x3.x) + c2*blo(x3.y) + c3*bhi(x3.y)
                    + c4*blo(x3.z) + c5*bhi(x3.z) + c6*blo(x3.w) + c7*bhi(x3.w);
            }
        }

        // Reduce within each 32-lane half (xor masks <= 16 stay in-half).
#pragma unroll
        for (int m = 16; m >= 1; m >>= 1) {
            a0 += __shfl_xor(a0, m);
            a1 += __shfl_xor(a1, m);
            a2 += __shfl_xor(a2, m);
            a3 += __shfl_xor(a3, m);
        }
        if (l5 == 0 && rowok) {
            const float sc = scales[r];
            atomicAdd(out + 0 * (size_t)OUT_F + r, sc * a0);
            atomicAdd(out + 1 * (size_t)OUT_F + r, sc * a1);
            atomicAdd(out + 2 * (size_t)OUT_F + r, sc * a2);
            atomicAdd(out + 3 * (size_t)OUT_F + r, sc * a3);
        }
    }
}

extern "C" void kernel_launch(void* const* d_in, const int* in_sizes, int n_in,
                              void* d_out, int out_size, void* d_ws, size_t ws_size,
                              hipStream_t stream) {
    const float* x      = (const float*)d_in[0];   // (4, 4096)
    const float* cb     = (const float*)d_in[1];   // (1, 65536, 1, 8)
    const int*   codes  = (const int*)d_in[2];     // (11008, 512, 1)
    const float* scales = (const float*)d_in[3];   // (11008, 1, 1, 1)
    const float* bias   = (const float*)d_in[4];   // (11008,)
    float* out = (float*)d_out;                    // (4, 11008)

    // ws layout: cbh 1 MB | buckets 67.6 MB | counts 704 KB  (ws ~256 MB)
    unsigned* cbh     = (unsigned*)d_ws;
    unsigned* buckets = (unsigned*)((char*)d_ws + (1u << 20));
    unsigned* counts  = (unsigned*)((char*)d_ws + (1u << 20)
                          + (size_t)OUT_F * NSLICE * CAP * 4u);

    hipLaunchKernelGGL(pack_cb_kernel, dim3(CBSIZE / 256), dim3(256), 0, stream,
                       cb, cbh);
    hipLaunchKernelGGL(bin_kernel, dim3(OUT_F), dim3(64), 0, stream,
                       codes, buckets, counts);
    hipLaunchKernelGGL(init_out_kernel, dim3(OTILES, BATCH), dim3(256), 0, stream,
                       bias, out);
    hipLaunchKernelGGL(main_kernel, dim3(ROWBLK, NSLICE), dim3(1024),
                       96 * 1024, stream,
                       x, cbh, buckets, counts, scales, out);
}

// Round 8
// 46.836 us; speedup vs baseline: 2.6309x; 2.6309x over previous
//
#include <hip/hip_runtime.h>

#define IN_F    4096
#define OUT_F   11008
#define NGROUP  512        // IN_F / 8
#define CHUNK   8          // groups per thread per block
#define NCHUNK  (NGROUP / CHUNK)   // 64
#define OTILES  (OUT_F / 256)      // 43
#define BATCH   4

typedef int   iv4 __attribute__((ext_vector_type(4)));
typedef float fv4 __attribute__((ext_vector_type(4)));

// out[b][o] = bias[o]
__global__ __launch_bounds__(256) void init_out_kernel(
    const float* __restrict__ bias, float* __restrict__ out)
{
    const int o = blockIdx.x * 256 + threadIdx.x;          // 43*256 = 11008 exactly
    out[(size_t)blockIdx.y * OUT_F + o] = bias[o];
}

// Each thread: one output o, CHUNK=8 consecutive groups starting at g0.
// 16 dwordx4 gathers in flight per wave (2 per code, same 64-B line -> 1 fill),
// sched_barrier-pinned. 2752 blocks = 10.75/CU cuts the dispatch tail that
// 1376 blocks (5.375/CU) had.
__global__ __launch_bounds__(256) void aqlm_kernel(
    const float* __restrict__ x,        // [4][4096]
    const float* __restrict__ cb,       // [65536][8]
    const int*   __restrict__ codes,    // [11008][512]
    const float* __restrict__ scales,   // [11008]
    float*       __restrict__ out)      // [4][11008]
{
    const int o  = blockIdx.x * 256 + threadIdx.x;
    const int g0 = blockIdx.y * CHUNK;

    // This lane's 8 codes: 32 B of one 64-B cache line (pair block reads the rest).
    int code[CHUNK];
    const iv4* cp = (const iv4*)(codes + (size_t)o * NGROUP + g0);
#pragma unroll
    for (int j = 0; j < CHUNK / 4; ++j) {
        const iv4 c = cp[j];
        code[4 * j + 0] = c.x;
        code[4 * j + 1] = c.y;
        code[4 * j + 2] = c.z;
        code[4 * j + 3] = c.w;
    }

    // Phase 1: issue all 16 dwordx4 gathers into registers.
    fv4 w0[CHUNK], w1[CHUNK];
#pragma unroll
    for (int j = 0; j < CHUNK; ++j) {
        const fv4* e = (const fv4*)(cb + (size_t)(unsigned)code[j] * 8u);
        w0[j] = e[0];
        w1[j] = e[1];
    }

    // Pin: no FMA may be hoisted above, no load may be sunk below.
    __builtin_amdgcn_sched_barrier(0);

    // Phase 2: FMA. x slices are wave-uniform -> scalar loads.
    float acc[BATCH];
#pragma unroll
    for (int b = 0; b < BATCH; ++b) acc[b] = 0.f;

#pragma unroll
    for (int j = 0; j < CHUNK; ++j) {
        const float* xg = x + (size_t)(g0 + j) * 8;
#pragma unroll
        for (int b = 0; b < BATCH; ++b) {
            const float* xb = xg + b * IN_F;
            acc[b] += xb[0] * w0[j].x + xb[1] * w0[j].y
                    + xb[2] * w0[j].z + xb[3] * w0[j].w
                    + xb[4] * w1[j].x + xb[5] * w1[j].y
                    + xb[6] * w1[j].z + xb[7] * w1[j].w;
        }
    }

    const float s = scales[o];
    atomicAdd(out + 0 * (size_t)OUT_F + o, s * acc[0]);
    atomicAdd(out + 1 * (size_t)OUT_F + o, s * acc[1]);
    atomicAdd(out + 2 * (size_t)OUT_F + o, s * acc[2]);
    atomicAdd(out + 3 * (size_t)OUT_F + o, s * acc[3]);
}

extern "C" void kernel_launch(void* const* d_in, const int* in_sizes, int n_in,
                              void* d_out, int out_size, void* d_ws, size_t ws_size,
                              hipStream_t stream) {
    const float* x      = (const float*)d_in[0];   // (4, 4096)
    const float* cb     = (const float*)d_in[1];   // (1, 65536, 1, 8)
    const int*   codes  = (const int*)d_in[2];     // (11008, 512, 1)
    const float* scales = (const float*)d_in[3];   // (11008, 1, 1, 1)
    const float* bias   = (const float*)d_in[4];   // (11008,)
    float* out = (float*)d_out;                    // (4, 11008)

    hipLaunchKernelGGL(init_out_kernel, dim3(OTILES, BATCH), dim3(256), 0, stream,
                       bias, out);
    hipLaunchKernelGGL(aqlm_kernel, dim3(OTILES, NCHUNK), dim3(256), 0, stream,
                       x, cb, codes, scales, out);
}

// Round 9
// 43.906 us; speedup vs baseline: 2.8065x; 1.0667x over previous
//
#include <hip/hip_runtime.h>

#define IN_F    4096
#define OUT_F   11008
#define NGROUP  512        // IN_F / 8
#define CHUNK   16         // groups per thread per block
#define NCHUNK  (NGROUP / CHUNK)   // 32
#define OTILES  (OUT_F / 256)      // 43
#define BATCH   4

typedef int   iv4 __attribute__((ext_vector_type(4)));
typedef float fv4 __attribute__((ext_vector_type(4)));

// out[b][o] = bias[o]
__global__ __launch_bounds__(256) void init_out_kernel(
    const float* __restrict__ bias, float* __restrict__ out)
{
    const int o = blockIdx.x * 256 + threadIdx.x;          // 43*256 = 11008 exactly
    out[(size_t)blockIdx.y * OUT_F + o] = bias[o];
}

// Each thread: one output o, CHUNK=16 consecutive groups starting at g0.
// One fully-used 64-B code line per lane; all 32 dwordx4 cb gathers issued
// before any FMA (sched_barrier-pinned). Bound by the per-CU outstanding
// line-fill cap on random gathers (~22k fills/CU x ~4.4 cyc) — MLP depth,
// request width, sc0, and occupancy all measured null (R4/R5/R6/R8).
__global__ __launch_bounds__(256) void aqlm_kernel(
    const float* __restrict__ x,        // [4][4096]
    const float* __restrict__ cb,       // [65536][8]
    const int*   __restrict__ codes,    // [11008][512]
    const float* __restrict__ scales,   // [11008]
    float*       __restrict__ out)      // [4][11008]
{
    const int o  = blockIdx.x * 256 + threadIdx.x;
    const int g0 = blockIdx.y * CHUNK;

    int code[CHUNK];
    const iv4* cp = (const iv4*)(codes + (size_t)o * NGROUP + g0);
#pragma unroll
    for (int j = 0; j < CHUNK / 4; ++j) {
        const iv4 c = cp[j];
        code[4 * j + 0] = c.x;
        code[4 * j + 1] = c.y;
        code[4 * j + 2] = c.z;
        code[4 * j + 3] = c.w;
    }

    // Phase 1: issue all 32 dwordx4 gathers into registers.
    fv4 w0[CHUNK], w1[CHUNK];
#pragma unroll
    for (int j = 0; j < CHUNK; ++j) {
        const fv4* e = (const fv4*)(cb + (size_t)(unsigned)code[j] * 8u);
        w0[j] = e[0];
        w1[j] = e[1];
    }

    // Pin: no FMA may be hoisted above, no load may be sunk below.
    __builtin_amdgcn_sched_barrier(0);

    // Phase 2: FMA. x slices are wave-uniform -> scalar loads.
    float acc[BATCH];
#pragma unroll
    for (int b = 0; b < BATCH; ++b) acc[b] = 0.f;

#pragma unroll
    for (int j = 0; j < CHUNK; ++j) {
        const float* xg = x + (size_t)(g0 + j) * 8;
#pragma unroll
        for (int b = 0; b < BATCH; ++b) {
            const float* xb = xg + b * IN_F;
            acc[b] += xb[0] * w0[j].x + xb[1] * w0[j].y
                    + xb[2] * w0[j].z + xb[3] * w0[j].w
                    + xb[4] * w1[j].x + xb[5] * w1[j].y
                    + xb[6] * w1[j].z + xb[7] * w1[j].w;
        }
    }

    const float s = scales[o];
    atomicAdd(out + 0 * (size_t)OUT_F + o, s * acc[0]);
    atomicAdd(out + 1 * (size_t)OUT_F + o, s * acc[1]);
    atomicAdd(out + 2 * (size_t)OUT_F + o, s * acc[2]);
    atomicAdd(out + 3 * (size_t)OUT_F + o, s * acc[3]);
}

extern "C" void kernel_launch(void* const* d_in, const int* in_sizes, int n_in,
                              void* d_out, int out_size, void* d_ws, size_t ws_size,
                              hipStream_t stream) {
    const float* x      = (const float*)d_in[0];   // (4, 4096)
    const float* cb     = (const float*)d_in[1];   // (1, 65536, 1, 8)
    const int*   codes  = (const int*)d_in[2];     // (11008, 512, 1)
    const float* scales = (const float*)d_in[3];   // (11008, 1, 1, 1)
    const float* bias   = (const float*)d_in[4];   // (11008,)
    float* out = (float*)d_out;                    // (4, 11008)

    hipLaunchKernelGGL(init_out_kernel, dim3(OTILES, BATCH), dim3(256), 0, stream,
                       bias, out);
    hipLaunchKernelGGL(aqlm_kernel, dim3(OTILES, NCHUNK), dim3(256), 0, stream,
                       x, cb, codes, scales, out);
}